// Round 1
// baseline (2173.025 us; speedup 1.0000x reference)
//
#include <hip/hip_runtime.h>
#include <hip/hip_bf16.h>
#include <cstdint>

#define B_ 4
#define LU_ 1024
#define LE_ 1024
#define D_ 512
#define H_ 8
#define HD_ 64

// ---------------- GEMM: C = scale * (A @ W + bias) ----------------
// A: [M,K] row-major, W: [K,N] row-major, bias: [N], C: [M,N]
__global__ __launch_bounds__(256) void gemm_bias(
    const float* __restrict__ A, const float* __restrict__ W,
    const float* __restrict__ bias, float* __restrict__ C,
    int M, int N, int K, float scale)
{
  __shared__ float As[16][65];  // [k][m], pad 65 breaks bank aliasing
  __shared__ float Ws[16][68];  // [k][n], pad 68 keeps float4 alignment
  const int t  = threadIdx.x;
  const int tx = t & 15;
  const int ty = t >> 4;
  const int bm = blockIdx.x * 64;
  const int bn = blockIdx.y * 64;

  float acc[4][4] = {};

  for (int k0 = 0; k0 < K; k0 += 16) {
    {
      const int m  = t >> 2;
      const int kk = (t & 3) * 4;
      float4 av = *(const float4*)(A + (size_t)(bm + m) * K + k0 + kk);
      As[kk + 0][m] = av.x;
      As[kk + 1][m] = av.y;
      As[kk + 2][m] = av.z;
      As[kk + 3][m] = av.w;
    }
    {
      const int kk = t >> 4;
      const int n  = (t & 15) * 4;
      float4 wv = *(const float4*)(W + (size_t)(k0 + kk) * N + bn + n);
      *(float4*)&Ws[kk][n] = wv;
    }
    __syncthreads();
#pragma unroll
    for (int kk = 0; kk < 16; ++kk) {
      float a[4], w[4];
#pragma unroll
      for (int i = 0; i < 4; ++i) a[i] = As[kk][ty + 16 * i];
#pragma unroll
      for (int j = 0; j < 4; ++j) w[j] = Ws[kk][tx + 16 * j];
#pragma unroll
      for (int i = 0; i < 4; ++i)
#pragma unroll
        for (int j = 0; j < 4; ++j) acc[i][j] += a[i] * w[j];
    }
    __syncthreads();
  }

#pragma unroll
  for (int i = 0; i < 4; ++i) {
    const int m = bm + ty + 16 * i;
#pragma unroll
    for (int j = 0; j < 4; ++j) {
      const int n = bn + tx + 16 * j;
      C[(size_t)m * N + n] = scale * (acc[i][j] + bias[n]);
    }
  }
}

// ---------------- Flash attention (fp32, online softmax) ----------------
// Q,K,V: [B, L, H, HD]; mask: [B,1,LQ,LK] int32 (0/1); bpp: [1024,1024]
// trans==0: bias = bw*bpp[qg*1024+kg]+bb ; trans==1: bias = bw*bpp[kg*1024+qg]+bb
// ctx out: [B, LQ, H, HD], rows already divided by softmax denom, masked cols = 0.
__global__ __launch_bounds__(256) void attn_flash(
    const float* __restrict__ Q,
    const float* __restrict__ Kg,
    const float* __restrict__ Vg,
    const int* __restrict__ mask,
    const float* __restrict__ bpp,
    const float* __restrict__ bpp_w, const float* __restrict__ bpp_b,
    float* __restrict__ ctx,
    int LQ, int LK, int trans)
{
  __shared__ float Ks[64][65];
  __shared__ float Vs[64][65];
  __shared__ float Ss[32][65];

  const int t  = threadIdx.x;
  const int b  = blockIdx.z;
  const int h  = blockIdx.y;
  const int q0 = blockIdx.x * 32;
  const int qi = t >> 3;            // local q row 0..31 (8 lanes per row)
  const int c  = t & 7;             // subgroup lane 0..7
  const int qg = q0 + qi;
  const float bw = *bpp_w;
  const float bb = *bpp_b;

  // q row (shared by the 8 lanes of the group) into registers
  float qreg[64];
  {
    const float* qp = Q + (((size_t)b * LQ + qg) * H_ + h) * HD_;
#pragma unroll
    for (int d = 0; d < 64; d += 4) {
      float4 qv = *(const float4*)(qp + d);
      qreg[d + 0] = qv.x; qreg[d + 1] = qv.y;
      qreg[d + 2] = qv.z; qreg[d + 3] = qv.w;
    }
  }

  float m_run = -3.0e38f;
  float l_run = 0.f;
  float O[8] = {};
  const int dbase = c * 8;          // this thread owns d = dbase..dbase+7

  for (int k0 = 0; k0 < LK; k0 += 64) {
    __syncthreads();                // prev PV done before K/V overwrite
    {
      const int row = t >> 2;
      const int cb  = (t & 3) * 16;
      const float* kp = Kg + (((size_t)b * LK + k0 + row) * H_ + h) * HD_ + cb;
      const float* vp = Vg + (((size_t)b * LK + k0 + row) * H_ + h) * HD_ + cb;
#pragma unroll
      for (int j = 0; j < 16; j += 4) {
        float4 kv = *(const float4*)(kp + j);
        float4 vv = *(const float4*)(vp + j);
        Ks[row][cb + j + 0] = kv.x; Ks[row][cb + j + 1] = kv.y;
        Ks[row][cb + j + 2] = kv.z; Ks[row][cb + j + 3] = kv.w;
        Vs[row][cb + j + 0] = vv.x; Vs[row][cb + j + 1] = vv.y;
        Vs[row][cb + j + 2] = vv.z; Vs[row][cb + j + 3] = vv.w;
      }
    }
    __syncthreads();

    // scores: this thread covers keys k0 + c*8 .. +7 for q row qi
    float s[8] = {};
#pragma unroll
    for (int d = 0; d < 64; ++d) {
      const float qv = qreg[d];
#pragma unroll
      for (int j = 0; j < 8; ++j) s[j] += qv * Ks[c * 8 + j][d];
    }

    float smax = -3.0e38f;
    const int kb = k0 + c * 8;
#pragma unroll
    for (int j = 0; j < 8; ++j) {
      const int kg = kb + j;
      const float bias = trans ? bpp[(size_t)kg * 1024 + qg]
                               : bpp[(size_t)qg * 1024 + kg];
      const int mk = mask[((size_t)b * LQ + qg) * LK + kg];
      s[j] = mk ? (s[j] + bw * bias + bb) : -3.0e38f;
      smax = fmaxf(smax, s[j]);
    }
#pragma unroll
    for (int off = 1; off < 8; off <<= 1)
      smax = fmaxf(smax, __shfl_xor(smax, off, 64));

    const float m_new = fmaxf(m_run, smax);
    float p[8];
    float psum = 0.f;
#pragma unroll
    for (int j = 0; j < 8; ++j) {
      p[j] = (s[j] > -1.0e37f) ? __expf(s[j] - m_new) : 0.f;  // masked -> exactly 0
      psum += p[j];
    }
#pragma unroll
    for (int off = 1; off < 8; off <<= 1)
      psum += __shfl_xor(psum, off, 64);

    const float alpha = __expf(m_run - m_new);  // 0 on first real chunk, 1 if no change
    l_run = l_run * alpha + psum;
    m_run = m_new;
#pragma unroll
    for (int j = 0; j < 8; ++j) O[j] *= alpha;

#pragma unroll
    for (int j = 0; j < 8; ++j) Ss[qi][c * 8 + j] = p[j];
    __syncthreads();

    // PV: O[d] += sum_k P[q][k] * V[k][d]
#pragma unroll
    for (int kk = 0; kk < 64; ++kk) {
      const float pv = Ss[qi][kk];
#pragma unroll
      for (int j = 0; j < 8; ++j) O[j] += pv * Vs[kk][dbase + j];
    }
  }

  const float inv = (l_run > 0.f) ? 1.f / l_run : 0.f;  // fully-masked row -> 0
  float* op = ctx + (((size_t)b * LQ + qg) * H_ + h) * HD_ + dbase;
  float4 o0 = make_float4(O[0] * inv, O[1] * inv, O[2] * inv, O[3] * inv);
  float4 o1 = make_float4(O[4] * inv, O[5] * inv, O[6] * inv, O[7] * inv);
  *(float4*)(op + 0) = o0;
  *(float4*)(op + 4) = o1;
}

extern "C" void kernel_launch(void* const* d_in, const int* in_sizes, int n_in,
                              void* d_out, int out_size, void* d_ws, size_t ws_size,
                              hipStream_t stream) {
  const float* u_enc     = (const float*)d_in[0];
  const float* e_enc     = (const float*)d_in[1];
  const float* logit_bpp = (const float*)d_in[2];
  const int*   ue_mask   = (const int*)d_in[3];
  const int*   eu_mask   = (const int*)d_in[4];
  const float* wq_k = (const float*)d_in[5];
  const float* wq_b = (const float*)d_in[6];
  const float* wk_k = (const float*)d_in[7];
  const float* wk_b = (const float*)d_in[8];
  const float* wv_k = (const float*)d_in[9];
  const float* wv_b = (const float*)d_in[10];
  const float* wo_k = (const float*)d_in[11];
  const float* wo_b = (const float*)d_in[12];
  const float* bpp_w = (const float*)d_in[13];
  const float* bpp_b = (const float*)d_in[14];

  float* out = (float*)d_out;
  float* ws  = (float*)d_ws;

  const size_t M2 = (size_t)B_ * LU_ * H_ * HD_;  // 2,097,152 elements
  float* q_u   = ws + 0 * M2;
  float* q_e   = ws + 1 * M2;
  float* k_u   = ws + 2 * M2;
  float* k_e   = ws + 3 * M2;
  float* v_u   = ws + 4 * M2;
  float* v_e   = ws + 5 * M2;
  float* u_ctx = ws + 6 * M2;
  float* e_ctx = ws + 7 * M2;

  const int M = B_ * LU_;       // 4096
  const int N = H_ * HD_;       // 512
  const int K = D_;             // 512
  const float scale = 0.125f;   // 1/sqrt(HD)

  dim3 gg(M / 64, N / 64), gb(256);
  gemm_bias<<<gg, gb, 0, stream>>>(u_enc, wq_k, wq_b, q_u, M, N, K, scale);
  gemm_bias<<<gg, gb, 0, stream>>>(e_enc, wq_k, wq_b, q_e, M, N, K, scale);
  gemm_bias<<<gg, gb, 0, stream>>>(u_enc, wk_k, wk_b, k_u, M, N, K, 1.0f);
  gemm_bias<<<gg, gb, 0, stream>>>(e_enc, wk_k, wk_b, k_e, M, N, K, 1.0f);
  gemm_bias<<<gg, gb, 0, stream>>>(u_enc, wv_k, wv_b, v_u, M, N, K, 1.0f);
  gemm_bias<<<gg, gb, 0, stream>>>(e_enc, wv_k, wv_b, v_e, M, N, K, 1.0f);

  dim3 ag(LU_ / 32, H_, B_);
  attn_flash<<<ag, gb, 0, stream>>>(q_u, k_e, v_e, ue_mask, logit_bpp,
                                    bpp_w, bpp_b, u_ctx, LU_, LE_, 0);
  attn_flash<<<ag, gb, 0, stream>>>(q_e, k_u, v_u, eu_mask, logit_bpp,
                                    bpp_w, bpp_b, e_ctx, LE_, LU_, 1);

  // output projection: wo_k viewed as [H*HD, D] row-major
  gemm_bias<<<gg, gb, 0, stream>>>(u_ctx, wo_k, wo_b, out,      M, D_, N, 1.0f);
  gemm_bias<<<gg, gb, 0, stream>>>(e_ctx, wo_k, wo_b, out + M2, M, D_, N, 1.0f);
}

// Round 2
// 301.646 us; speedup vs baseline: 7.2039x; 7.2039x over previous
//
#include <hip/hip_runtime.h>
#include <hip/hip_bf16.h>
#include <cstdint>

typedef unsigned short u16;
typedef __attribute__((ext_vector_type(8))) short short8;
typedef __attribute__((ext_vector_type(4))) float floatx4;

#define MFMA16(a, b, c) __builtin_amdgcn_mfma_f32_16x16x32_bf16(a, b, c, 0, 0, 0)

#define B_ 4
#define L_ 1024
#define H_ 8
#define HD_ 64
#define D_ 512

__device__ __forceinline__ u16 f2bf(float v) {
  union { float f; unsigned u; } x; x.f = v;
  unsigned r = x.u + 0x7FFF + ((x.u >> 16) & 1);   // RNE
  return (u16)(r >> 16);
}
__device__ __forceinline__ float bf2f(u16 v) {
  union { unsigned u; float f; } x; x.u = ((unsigned)v) << 16; return x.f;
}

__device__ __forceinline__ void gload_lds16(const u16* g, u16* l) {
  __builtin_amdgcn_global_load_lds(
      (const __attribute__((address_space(1))) unsigned int*)(g),
      (__attribute__((address_space(3))) unsigned int*)(l), 16, 0, 0);
}

// ---------- fp32 -> bf16 elementwise ----------
__global__ __launch_bounds__(256) void cvt_bf16(const float* __restrict__ src,
                                                u16* __restrict__ dst, int n) {
  int i = (blockIdx.x * 256 + threadIdx.x) * 4;
  if (i < n) {
    float4 v = *(const float4*)(src + i);
    u16 o0 = f2bf(v.x), o1 = f2bf(v.y), o2 = f2bf(v.z), o3 = f2bf(v.w);
    ushort4 o = make_ushort4(o0, o1, o2, o3);
    *(ushort4*)(dst + i) = o;
  }
}

// ---------- [512][512] fp32 -> transposed bf16 [n][k] ----------
__global__ __launch_bounds__(256) void trans_cvt(const float* __restrict__ src,
                                                 u16* __restrict__ dst, float scale) {
  __shared__ float t[32][33];
  int k0 = blockIdx.x * 32, n0 = blockIdx.y * 32;
  int tx = threadIdx.x & 31, ty = threadIdx.x >> 5;  // 32 x 8
#pragma unroll
  for (int i = 0; i < 32; i += 8) t[ty + i][tx] = src[(size_t)(k0 + ty + i) * 512 + n0 + tx];
  __syncthreads();
#pragma unroll
  for (int i = 0; i < 32; i += 8)
    dst[(size_t)(n0 + ty + i) * 512 + k0 + tx] = f2bf(scale * t[tx][ty + i]);
}

// ---------- concat+scale biases: [0.125*bq | bk | bv] ----------
__global__ __launch_bounds__(256) void bias_cat(const float* __restrict__ q,
                                                const float* __restrict__ k,
                                                const float* __restrict__ v,
                                                float* __restrict__ dst) {
  int n = blockIdx.x * 256 + threadIdx.x;  // 1536
  float val = (n < 512) ? 0.125f * q[n] : ((n < 1024) ? k[n - 512] : v[n - 1024]);
  dst[n] = val;
}

// ---------- biasmask: bm[b][q][k] = mask ? bw*bias+bb : -1e30 (bf16) ----------
__global__ __launch_bounds__(256) void build_bm(const int* __restrict__ mask,
                                                const float* __restrict__ bpp,
                                                const float* __restrict__ bw_p,
                                                const float* __restrict__ bb_p,
                                                u16* __restrict__ bm, int trans) {
  size_t i = (size_t)blockIdx.x * 256 + threadIdx.x;  // 4*1024*1024
  int k = (int)(i & 1023), q = (int)((i >> 10) & 1023);
  float bias = trans ? bpp[(size_t)k * 1024 + q] : bpp[(size_t)q * 1024 + k];
  float v = mask[i] ? ((*bw_p) * bias + (*bb_p)) : -1e30f;
  bm[i] = f2bf(v);
}

// ---------- MFMA GEMM: C[m][n] = A[m][:] . Bt[n][:] + bias[n] ----------
// MODE 0: QKV epilogue (bf16 -> q/k/vt buffers); MODE 1: fp32 -> out
template <int MODE>
__global__ __launch_bounds__(256) void gemm_mfma(
    const u16* __restrict__ A,    // [M][K] bf16 k-major
    const u16* __restrict__ Bt,   // [N][K] bf16 k-major
    const float* __restrict__ bias,
    float* __restrict__ outf, u16* __restrict__ q_out,
    u16* __restrict__ k_out, u16* __restrict__ vt_out, int K) {
  __shared__ u16 As[128 * 32];
  __shared__ u16 Bs[128 * 32];
  const int t = threadIdx.x, lane = t & 63, wave = t >> 6;
  const int l15 = lane & 15, quad = lane >> 4;
  const int wy = wave >> 1, wx = wave & 1;
  const int m0 = blockIdx.x * 128, n0 = blockIdx.y * 128;
  (void)lane;

  floatx4 zero4 = {0.f, 0.f, 0.f, 0.f};
  floatx4 acc[4][4];
#pragma unroll
  for (int mi = 0; mi < 4; ++mi)
#pragma unroll
    for (int ni = 0; ni < 4; ++ni) acc[mi][ni] = zero4;

  for (int k0 = 0; k0 < K; k0 += 32) {
    __syncthreads();
    {
      int s = t;
#pragma unroll
      for (int i = 0; i < 2; ++i, s += 256) {
        int row = s >> 2, seg = s & 3;
        gload_lds16(A + (size_t)(m0 + row) * K + k0 + seg * 8, &As[s * 8]);
      }
      s = t;
#pragma unroll
      for (int i = 0; i < 2; ++i, s += 256) {
        int row = s >> 2, seg = s & 3;
        gload_lds16(Bt + (size_t)(n0 + row) * K + k0 + seg * 8, &Bs[s * 8]);
      }
    }
    __syncthreads();
    short8 af[4], bf[4];
#pragma unroll
    for (int mi = 0; mi < 4; ++mi)
      af[mi] = *(const short8*)&As[(wy * 64 + mi * 16 + l15) * 32 + quad * 8];
#pragma unroll
    for (int ni = 0; ni < 4; ++ni)
      bf[ni] = *(const short8*)&Bs[(wx * 64 + ni * 16 + l15) * 32 + quad * 8];
#pragma unroll
    for (int mi = 0; mi < 4; ++mi)
#pragma unroll
      for (int ni = 0; ni < 4; ++ni) acc[mi][ni] = MFMA16(af[mi], bf[ni], acc[mi][ni]);
  }

#pragma unroll
  for (int mi = 0; mi < 4; ++mi)
#pragma unroll
    for (int ni = 0; ni < 4; ++ni) {
      int n = n0 + wx * 64 + ni * 16 + l15;
      float bv = bias[n];
#pragma unroll
      for (int r = 0; r < 4; ++r) {
        int m = m0 + wy * 64 + mi * 16 + quad * 4 + r;
        float v = acc[mi][ni][r] + bv;
        if (MODE == 1) {
          outf[(size_t)m * 512 + n] = v;
        } else {
          int sel = n >> 9, c = n & 511;
          u16 hv = f2bf(v);
          if (sel == 0) q_out[(size_t)m * 512 + c] = hv;
          else if (sel == 1) k_out[(size_t)m * 512 + c] = hv;
          else {
            int b = m >> 10, l = m & 1023, h = c >> 6, hd = c & 63;
            vt_out[(((size_t)b * H_ + h) * HD_ + hd) * 1024 + l] = hv;
          }
        }
      }
    }
}

// ---------- MFMA flash attention ----------
// Q [B,LQ,H,64] bf16, Kb [B,LK,H,64] bf16, Vt [B,H,64,LK] bf16,
// bm [B,LQ,LK] bf16 (bias or -1e30), ctx out [B,LQ,H,64] bf16
__global__ __launch_bounds__(256) void attn_mfma(
    const u16* __restrict__ Q, const u16* __restrict__ Kb,
    const u16* __restrict__ Vt, const u16* __restrict__ bm,
    u16* __restrict__ ctx, int LQ, int LK) {
  __shared__ u16 Ks[64 * 64];
  __shared__ u16 Vs[64 * 64];
  __shared__ u16 Ps[4][16 * 72];  // per-wave, padded rows (144B)
  const int t = threadIdx.x, lane = t & 63, wave = t >> 6;
  const int l15 = lane & 15, quad = lane >> 4;
  const int b = blockIdx.z, h = blockIdx.y, q0 = blockIdx.x * 64;
  const int qbase = q0 + wave * 16;

  short8 qa0, qa1;
  {
    const u16* qp = Q + ((size_t)(b * LQ + qbase + l15) * H_ + h) * HD_ + quad * 8;
    qa0 = *(const short8*)qp;
    qa1 = *(const short8*)(qp + 32);
  }

  floatx4 zero4 = {0.f, 0.f, 0.f, 0.f};
  floatx4 O[4];
  float m_run[4], l_run[4];
#pragma unroll
  for (int i = 0; i < 4; ++i) { O[i] = zero4; m_run[i] = -1e30f; l_run[i] = 0.f; }

  for (int k0 = 0; k0 < LK; k0 += 64) {
    __syncthreads();
    {
      int s = t;
#pragma unroll
      for (int i = 0; i < 2; ++i, s += 256) {
        int row = s >> 3, pseg = s & 7, lseg = pseg ^ (row & 7);  // XOR swizzle
        gload_lds16(Kb + ((size_t)(b * LK + k0 + row) * H_ + h) * HD_ + lseg * 8,
                    &Ks[s * 8]);
        gload_lds16(Vt + (((size_t)b * H_ + h) * HD_ + row) * (size_t)LK + k0 + lseg * 8,
                    &Vs[s * 8]);
      }
    }
    __syncthreads();

    // ---- S = Q . K^T ----
    floatx4 S[4];
#pragma unroll
    for (int kb = 0; kb < 4; ++kb) S[kb] = zero4;
#pragma unroll
    for (int kb = 0; kb < 4; ++kb) {
      int krow = kb * 16 + l15;
      int ps0 = (quad) ^ (krow & 7);
      int ps1 = (4 + quad) ^ (krow & 7);
      short8 b0 = *(const short8*)&Ks[krow * 64 + ps0 * 8];
      short8 b1 = *(const short8*)&Ks[krow * 64 + ps1 * 8];
      S[kb] = MFMA16(qa0, b0, S[kb]);
      S[kb] = MFMA16(qa1, b1, S[kb]);
    }

    // ---- bias/mask + online softmax (rows quad*4+r, key kb*16+l15) ----
    float sv[4][4];
#pragma unroll
    for (int kb = 0; kb < 4; ++kb)
#pragma unroll
      for (int r = 0; r < 4; ++r) {
        float bb = bf2f(bm[((size_t)(b * LQ + qbase + quad * 4 + r)) * LK + k0 + kb * 16 + l15]);
        sv[kb][r] = S[kb][r] + bb;  // masked -> ~-1e30
      }

    float mnew[4], alpha[4];
#pragma unroll
    for (int r = 0; r < 4; ++r) {
      float mx = fmaxf(fmaxf(sv[0][r], sv[1][r]), fmaxf(sv[2][r], sv[3][r]));
#pragma unroll
      for (int off = 1; off < 16; off <<= 1) mx = fmaxf(mx, __shfl_xor(mx, off, 64));
      mnew[r] = fmaxf(m_run[r], mx);
      alpha[r] = __expf(m_run[r] - mnew[r]);
      m_run[r] = mnew[r];
    }

    float p[4][4], rsum[4] = {0.f, 0.f, 0.f, 0.f};
#pragma unroll
    for (int kb = 0; kb < 4; ++kb)
#pragma unroll
      for (int r = 0; r < 4; ++r) {
        float e = __expf(sv[kb][r] - mnew[r]);
        e = (sv[kb][r] > -1e29f) ? e : 0.f;  // masked -> exactly 0
        p[kb][r] = e;
        rsum[r] += e;
      }
#pragma unroll
    for (int r = 0; r < 4; ++r) {
#pragma unroll
      for (int off = 1; off < 16; off <<= 1) rsum[r] += __shfl_xor(rsum[r], off, 64);
      l_run[r] = l_run[r] * alpha[r] + rsum[r];
    }

    // ---- P -> per-wave LDS (C-layout write, A-layout read; no barrier) ----
#pragma unroll
    for (int kb = 0; kb < 4; ++kb)
#pragma unroll
      for (int r = 0; r < 4; ++r)
        Ps[wave][(quad * 4 + r) * 72 + kb * 16 + l15] = f2bf(p[kb][r]);

#pragma unroll
    for (int nb = 0; nb < 4; ++nb)
#pragma unroll
      for (int r = 0; r < 4; ++r) O[nb][r] *= alpha[r];

    short8 pa0 = *(const short8*)&Ps[wave][l15 * 72 + quad * 8];
    short8 pa1 = *(const short8*)&Ps[wave][l15 * 72 + 32 + quad * 8];

    // ---- O += P . V ----
#pragma unroll
    for (int nb = 0; nb < 4; ++nb) {
      int vrow = nb * 16 + l15;
      int ps0 = (quad) ^ (vrow & 7);
      int ps1 = (4 + quad) ^ (vrow & 7);
      short8 v0 = *(const short8*)&Vs[vrow * 64 + ps0 * 8];
      short8 v1 = *(const short8*)&Vs[vrow * 64 + ps1 * 8];
      O[nb] = MFMA16(pa0, v0, O[nb]);
      O[nb] = MFMA16(pa1, v1, O[nb]);
    }
  }

#pragma unroll
  for (int r = 0; r < 4; ++r) {
    float inv = (l_run[r] > 0.f) ? 1.f / l_run[r] : 0.f;
    int qd = qbase + quad * 4 + r;
    u16* cp = ctx + ((size_t)(b * LQ + qd) * H_ + h) * HD_;
#pragma unroll
    for (int nb = 0; nb < 4; ++nb) cp[nb * 16 + l15] = f2bf(O[nb][r] * inv);
  }
}

extern "C" void kernel_launch(void* const* d_in, const int* in_sizes, int n_in,
                              void* d_out, int out_size, void* d_ws, size_t ws_size,
                              hipStream_t stream) {
  const float* u_enc = (const float*)d_in[0];
  const float* e_enc = (const float*)d_in[1];
  const float* logit_bpp = (const float*)d_in[2];
  const int* ue_mask = (const int*)d_in[3];
  const int* eu_mask = (const int*)d_in[4];
  const float* wq_k = (const float*)d_in[5];
  const float* wq_b = (const float*)d_in[6];
  const float* wk_k = (const float*)d_in[7];
  const float* wk_b = (const float*)d_in[8];
  const float* wv_k = (const float*)d_in[9];
  const float* wv_b = (const float*)d_in[10];
  const float* wo_k = (const float*)d_in[11];
  const float* wo_b = (const float*)d_in[12];
  const float* bpp_w = (const float*)d_in[13];
  const float* bpp_b = (const float*)d_in[14];

  float* out = (float*)d_out;

  const size_t M2 = 2097152;  // 4096*512
  u16* ws16 = (u16*)d_ws;
  u16* ub = ws16;
  u16* eb = ub + M2;
  u16* Wqkvt = eb + M2;          // [1536][512]
  u16* Wot = Wqkvt + 786432;     // [512][512]
  u16* q_u = Wot + 262144;
  u16* k_u = q_u + M2;
  u16* vt_u = k_u + M2;
  u16* q_e = vt_u + M2;
  u16* k_e = q_e + M2;
  u16* vt_e = k_e + M2;
  u16* ctx_u = vt_e + M2;
  u16* ctx_e = ctx_u + M2;
  u16* bm_ue = ctx_e + M2;       // 4M
  u16* bm_eu = bm_ue + 4194304;
  float* bqkv = (float*)(bm_eu + 4194304);  // 1536

  // conversions
  cvt_bf16<<<2048, 256, 0, stream>>>(u_enc, ub, (int)M2);
  cvt_bf16<<<2048, 256, 0, stream>>>(e_enc, eb, (int)M2);
  dim3 tg(16, 16);
  trans_cvt<<<tg, 256, 0, stream>>>(wq_k, Wqkvt, 0.125f);
  trans_cvt<<<tg, 256, 0, stream>>>(wk_k, Wqkvt + 512 * 512, 1.0f);
  trans_cvt<<<tg, 256, 0, stream>>>(wv_k, Wqkvt + 1024 * 512, 1.0f);
  trans_cvt<<<tg, 256, 0, stream>>>(wo_k, Wot, 1.0f);
  bias_cat<<<6, 256, 0, stream>>>(wq_b, wk_b, wv_b, bqkv);
  build_bm<<<16384, 256, 0, stream>>>(ue_mask, logit_bpp, bpp_w, bpp_b, bm_ue, 0);
  build_bm<<<16384, 256, 0, stream>>>(eu_mask, logit_bpp, bpp_w, bpp_b, bm_eu, 1);

  // fused QKV projections (N = 1536)
  dim3 gq(32, 12);
  gemm_mfma<0><<<gq, 256, 0, stream>>>(ub, Wqkvt, bqkv, nullptr, q_u, k_u, vt_u, 512);
  gemm_mfma<0><<<gq, 256, 0, stream>>>(eb, Wqkvt, bqkv, nullptr, q_e, k_e, vt_e, 512);

  // attention
  dim3 ga(16, 8, 4);
  attn_mfma<<<ga, 256, 0, stream>>>(q_u, k_e, vt_e, bm_ue, ctx_u, 1024, 1024);
  attn_mfma<<<ga, 256, 0, stream>>>(q_e, k_u, vt_u, bm_eu, ctx_e, 1024, 1024);

  // output projection (N = 512)
  dim3 go(32, 4);
  gemm_mfma<1><<<go, 256, 0, stream>>>(ctx_u, Wot, wo_b, out, nullptr, nullptr, nullptr, 512);
  gemm_mfma<1><<<go, 256, 0, stream>>>(ctx_e, Wot, wo_b, out + M2, nullptr, nullptr, nullptr, 512);
}

// Round 3
// 221.015 us; speedup vs baseline: 9.8320x; 1.3648x over previous
//
#include <hip/hip_runtime.h>
#include <hip/hip_bf16.h>
#include <cstdint>

typedef unsigned short u16;
typedef __attribute__((ext_vector_type(8))) short short8;
typedef __attribute__((ext_vector_type(4))) float floatx4;

#define MFMA16(a, b, c) __builtin_amdgcn_mfma_f32_16x16x32_bf16(a, b, c, 0, 0, 0)
#define LOG2E 1.4426950408889634f

__device__ __forceinline__ float fast_exp2(float x) {
#if __has_builtin(__builtin_amdgcn_exp2f)
  return __builtin_amdgcn_exp2f(x);
#else
  return exp2f(x);
#endif
}
__device__ __forceinline__ u16 f2bf(float v) {
  union { float f; unsigned u; } x; x.f = v;
  unsigned r = x.u + 0x7FFF + ((x.u >> 16) & 1);  // RNE
  return (u16)(r >> 16);
}
__device__ __forceinline__ float bf2f(u16 v) {
  union { unsigned u; float f; } x; x.u = ((unsigned)v) << 16; return x.f;
}
__device__ __forceinline__ void gload_lds16(const u16* g, u16* l) {
  __builtin_amdgcn_global_load_lds(
      (const __attribute__((address_space(1))) unsigned int*)(g),
      (__attribute__((address_space(3))) unsigned int*)(l), 16, 0, 0);
}

// ---------- fp32 -> bf16, both encoders in one launch ----------
__global__ __launch_bounds__(256) void cvt_bf16(const float* __restrict__ u,
                                                const float* __restrict__ e,
                                                u16* __restrict__ dst) {
  int i = (blockIdx.x * 256 + threadIdx.x) * 4;
  const float* s = blockIdx.y ? e : u;
  u16* d = dst + (size_t)blockIdx.y * 2097152;
  float4 v = *(const float4*)(s + i);
  ushort4 o = make_ushort4(f2bf(v.x), f2bf(v.y), f2bf(v.z), f2bf(v.w));
  *(ushort4*)(d + i) = o;
}

// ---------- all 4 weight matrices: [512][512] -> transposed bf16 [n][k] ----------
__global__ __launch_bounds__(256) void wtrans(const float* __restrict__ wq,
                                              const float* __restrict__ wk,
                                              const float* __restrict__ wv,
                                              const float* __restrict__ wo,
                                              u16* __restrict__ Wt) {
  __shared__ float tl[32][33];
  const float* src = blockIdx.z == 0 ? wq : blockIdx.z == 1 ? wk : blockIdx.z == 2 ? wv : wo;
  float scale = blockIdx.z == 0 ? 0.125f * LOG2E : 1.0f;
  u16* dst = Wt + (size_t)blockIdx.z * 262144;
  int k0 = blockIdx.x * 32, n0 = blockIdx.y * 32;
  int tx = threadIdx.x & 31, ty = threadIdx.x >> 5;
#pragma unroll
  for (int i = 0; i < 32; i += 8) tl[ty + i][tx] = src[(size_t)(k0 + ty + i) * 512 + n0 + tx];
  __syncthreads();
#pragma unroll
  for (int i = 0; i < 32; i += 8)
    dst[(size_t)(n0 + ty + i) * 512 + k0 + tx] = f2bf(scale * tl[tx][ty + i]);
}

// ---------- concat biases: [0.125*log2e*bq | bk | bv | bo] (2048 f32) ----------
__global__ __launch_bounds__(256) void bias_cat(const float* __restrict__ q,
                                                const float* __restrict__ k,
                                                const float* __restrict__ v,
                                                const float* __restrict__ o,
                                                float* __restrict__ dst) {
  int n = blockIdx.x * 256 + threadIdx.x;
  float val = n < 512 ? 0.125f * LOG2E * q[n]
            : n < 1024 ? k[n - 512]
            : n < 1536 ? v[n - 1024] : o[n - 1536];
  dst[n] = val;
}

// ---------- bppT[a][b] = bpp[b][a] ----------
__global__ __launch_bounds__(256) void bpp_t(const float* __restrict__ bpp,
                                             float* __restrict__ bppT) {
  __shared__ float tl[32][33];
  int a0 = blockIdx.x * 32, b0 = blockIdx.y * 32;
  int tx = threadIdx.x & 31, ty = threadIdx.x >> 5;
#pragma unroll
  for (int i = 0; i < 32; i += 8) tl[ty + i][tx] = bpp[(size_t)(b0 + ty + i) * 1024 + a0 + tx];
  __syncthreads();
#pragma unroll
  for (int i = 0; i < 32; i += 8) bppT[(size_t)(a0 + ty + i) * 1024 + b0 + tx] = tl[tx][ty + i];
}

// ---------- bias-mask in MFMA fragment layout, log2e-folded ----------
// bm[side][b][q16][kc][lane][i], i=kb*4+r -> (q=q16*16+quad*4+r, k=kc*128+kb*16+l15)
__global__ __launch_bounds__(256) void build_bm(const int* __restrict__ mu,
                                                const int* __restrict__ me,
                                                const float* __restrict__ bpp,
                                                const float* __restrict__ bppT,
                                                const float* __restrict__ bw_p,
                                                const float* __restrict__ bb_p,
                                                u16* __restrict__ bm) {
  int side = blockIdx.z >> 2, b = blockIdx.z & 3;
  const int* mask = side ? me : mu;
  const float* bp = side ? bppT : bpp;
  int kc = blockIdx.x;
  int q16 = blockIdx.y * 4 + (threadIdx.x >> 6);
  int lane = threadIdx.x & 63, l15 = lane & 15, quad = lane >> 4;
  float sw = (*bw_p) * LOG2E, sb = (*bb_p) * LOG2E;
  u16 vals[32];
#pragma unroll
  for (int i = 0; i < 32; ++i) {
    int kb = i >> 2, r = i & 3;
    int q = q16 * 16 + quad * 4 + r, k = kc * 128 + kb * 16 + l15;
    int m = mask[((size_t)b * 1024 + q) * 1024 + k];
    float bv = bp[(size_t)q * 1024 + k];
    vals[i] = f2bf(m ? sw * bv + sb : -1e30f);
  }
  u16* dst = bm + ((((size_t)side * 4 + b) * 64 + q16) * 8 + kc) * 2048 + (size_t)lane * 32;
#pragma unroll
  for (int j = 0; j < 4; ++j) *(short8*)(dst + j * 8) = *(const short8*)(vals + j * 8);
}

// ---------- MFMA GEMM (m97 structure), M=8192 fused ----------
// MODE 0: N=1536, epilogue -> q/k/v bf16 plain; MODE 1: N=512 -> fp32 out
template <int MODE>
__global__ __launch_bounds__(256) void gemm_mfma(
    const u16* __restrict__ A, const u16* __restrict__ Bt,
    const float* __restrict__ bias, float* __restrict__ outf,
    u16* __restrict__ q_o, u16* __restrict__ k_o, u16* __restrict__ v_o) {
  __shared__ u16 As[128 * 32];
  __shared__ u16 Bs[128 * 32];
  const int t = threadIdx.x, lane = t & 63, wave = t >> 6;
  const int l15 = lane & 15, quad = lane >> 4;
  const int wy = wave >> 1, wx = wave & 1;
  const int m0 = blockIdx.x * 128, n0 = blockIdx.y * 128;
  const int K = 512;

  floatx4 zero4 = {0.f, 0.f, 0.f, 0.f};
  floatx4 acc[4][4];
#pragma unroll
  for (int mi = 0; mi < 4; ++mi)
#pragma unroll
    for (int ni = 0; ni < 4; ++ni) acc[mi][ni] = zero4;

  for (int k0 = 0; k0 < K; k0 += 32) {
    __syncthreads();
    {
      int s = t;
#pragma unroll
      for (int i = 0; i < 2; ++i, s += 256) {
        int row = s >> 2, seg = s & 3;
        gload_lds16(A + (size_t)(m0 + row) * K + k0 + seg * 8, &As[s * 8]);
      }
      s = t;
#pragma unroll
      for (int i = 0; i < 2; ++i, s += 256) {
        int row = s >> 2, seg = s & 3;
        gload_lds16(Bt + (size_t)(n0 + row) * K + k0 + seg * 8, &Bs[s * 8]);
      }
    }
    __syncthreads();
    short8 af[4], bf[4];
#pragma unroll
    for (int mi = 0; mi < 4; ++mi)
      af[mi] = *(const short8*)&As[(wy * 64 + mi * 16 + l15) * 32 + quad * 8];
#pragma unroll
    for (int ni = 0; ni < 4; ++ni)
      bf[ni] = *(const short8*)&Bs[(wx * 64 + ni * 16 + l15) * 32 + quad * 8];
#pragma unroll
    for (int mi = 0; mi < 4; ++mi)
#pragma unroll
      for (int ni = 0; ni < 4; ++ni) acc[mi][ni] = MFMA16(af[mi], bf[ni], acc[mi][ni]);
  }

#pragma unroll
  for (int mi = 0; mi < 4; ++mi)
#pragma unroll
    for (int ni = 0; ni < 4; ++ni) {
      int n = n0 + wx * 64 + ni * 16 + l15;
      float bv = bias[n];
#pragma unroll
      for (int r = 0; r < 4; ++r) {
        int m = m0 + wy * 64 + mi * 16 + quad * 4 + r;
        float v = acc[mi][ni][r] + bv;
        if (MODE == 1) {
          outf[(size_t)m * 512 + n] = v;
        } else {
          int sel = n >> 9, c = n & 511;
          u16 hv = f2bf(v);
          if (sel == 0) q_o[(size_t)m * 512 + c] = hv;
          else if (sel == 1) k_o[(size_t)m * 512 + c] = hv;
          else v_o[(size_t)m * 512 + c] = hv;
        }
      }
    }
}

// ---------- v [m][h*64+hd] -> vt [half][b][h][hd][l] via LDS tile ----------
__global__ __launch_bounds__(256) void vt_trans(const u16* __restrict__ v_all,
                                                u16* __restrict__ vt_all) {
  __shared__ u16 tl[64][72];
  int z = blockIdx.z, half = z >> 2, b = z & 3, h = blockIdx.y, l0 = blockIdx.x * 64;
  const u16* src = v_all + (size_t)half * 2097152;
  u16* dst = vt_all + (size_t)half * 2097152;
  int t = threadIdx.x;
#pragma unroll
  for (int i = 0; i < 2; ++i) {
    int s = t + i * 256, row = s >> 3, seg = s & 7;
    *(short8*)&tl[row][seg * 8] =
        *(const short8*)(src + (size_t)(b * 1024 + l0 + row) * 512 + h * 64 + seg * 8);
  }
  __syncthreads();
#pragma unroll
  for (int i = 0; i < 2; ++i) {
    int s = t + i * 256, hd = s >> 3, seg = s & 7;
    u16 tmp[8];
#pragma unroll
    for (int j = 0; j < 8; ++j) tmp[j] = tl[seg * 8 + j][hd];
    *(short8*)(dst + ((size_t)(b * 8 + h) * 64 + hd) * 1024 + l0 + seg * 8) =
        *(const short8*)tmp;
  }
}

// ---------- MFMA flash attention, fixed-offset softmax, dbuf, both sides fused ----------
__global__ __launch_bounds__(256) void attn_mfma(
    const u16* __restrict__ q_all, const u16* __restrict__ k_all,
    const u16* __restrict__ vt_all, const u16* __restrict__ bm_all,
    u16* __restrict__ ctx_all) {
  __shared__ u16 Ks[2][128 * 64];
  __shared__ u16 Vs[2][64 * 128];
  __shared__ u16 Ps[4][16 * 128];
  const int t = threadIdx.x, lane = t & 63, wave = t >> 6;
  const int l15 = lane & 15, quad = lane >> 4;
  const int side = blockIdx.z >> 2, b = blockIdx.z & 3, h = blockIdx.y;
  const int q0 = blockIdx.x * 128;
  const size_t HALF = 2097152;
  const u16* Q = q_all + side * HALF;
  const u16* K = k_all + (1 - side) * HALF;
  const u16* Vt = vt_all + (1 - side) * HALF;
  const u16* bm = bm_all + side * (size_t)4194304;
  u16* ctx = ctx_all + side * HALF;
  const int qbase = q0 + wave * 32;
  const int q16_0 = qbase >> 4;

  short8 qa[2][2];
#pragma unroll
  for (int s = 0; s < 2; ++s) {
    const u16* qp = Q + (size_t)(b * 1024 + qbase + s * 16 + l15) * 512 + h * 64 + quad * 8;
    qa[s][0] = *(const short8*)qp;
    qa[s][1] = *(const short8*)(qp + 32);
  }

  short8 bones;
#pragma unroll
  for (int j = 0; j < 8; ++j) bones[j] = (short)0x3F80;

  floatx4 zero4 = {0.f, 0.f, 0.f, 0.f};
  floatx4 O[2][4], O5[2];
#pragma unroll
  for (int s = 0; s < 2; ++s) {
    O5[s] = zero4;
#pragma unroll
    for (int nb = 0; nb < 4; ++nb) O[s][nb] = zero4;
  }

#define STAGE(buf, k0)                                                              \
  {                                                                                 \
    _Pragma("unroll") for (int i = 0; i < 4; ++i) {                                 \
      int s = t + i * 256, row = s >> 3, pseg = s & 7, lseg = pseg ^ (row & 7);     \
      gload_lds16(K + (size_t)(b * 1024 + (k0) + row) * 512 + h * 64 + lseg * 8,    \
                  &Ks[buf][s * 8]);                                                 \
    }                                                                               \
    _Pragma("unroll") for (int i = 0; i < 4; ++i) {                                 \
      int s = t + i * 256, row = s >> 4, pseg = s & 15, lseg = pseg ^ (row & 15);   \
      gload_lds16(Vt + ((size_t)(b * 8 + h) * 64 + row) * 1024 + (k0) + lseg * 8,   \
                  &Vs[buf][s * 8]);                                                 \
    }                                                                               \
  }

  STAGE(0, 0)

  for (int it = 0; it < 8; ++it) {
    const int cur = it & 1;
    __syncthreads();
    if (it < 7) STAGE(cur ^ 1, it * 128 + 128)

    // bm fragment loads (vectorized, coalesced)
    short8 bmv[2][4];
#pragma unroll
    for (int s = 0; s < 2; ++s) {
      const u16* bp = bm + ((((size_t)b * 64 + q16_0 + s) * 8 + it) * 64 + lane) * 32;
#pragma unroll
      for (int j = 0; j < 4; ++j) bmv[s][j] = *(const short8*)(bp + j * 8);
    }

    // ---- S = Q.K^T - 64 (offset folded into accumulator init) ----
    floatx4 S[2][8];
#pragma unroll
    for (int s = 0; s < 2; ++s)
#pragma unroll
      for (int kb = 0; kb < 8; ++kb) S[s][kb] = (floatx4){-64.f, -64.f, -64.f, -64.f};
#pragma unroll
    for (int kb = 0; kb < 8; ++kb) {
      int krow = kb * 16 + l15;
      short8 b0 = *(const short8*)&Ks[cur][krow * 64 + (quad ^ (krow & 7)) * 8];
      short8 b1 = *(const short8*)&Ks[cur][krow * 64 + ((4 + quad) ^ (krow & 7)) * 8];
#pragma unroll
      for (int s = 0; s < 2; ++s) {
        S[s][kb] = MFMA16(qa[s][0], b0, S[s][kb]);
        S[s][kb] = MFMA16(qa[s][1], b1, S[s][kb]);
      }
    }

    // ---- p = exp2(S + bm); masked bm=-1e30 underflows to exact 0 ----
    short8 pa[2][4];
#pragma unroll
    for (int s = 0; s < 2; ++s) {
      u16* ps = &Ps[wave][0];
#pragma unroll
      for (int kb = 0; kb < 8; ++kb) {
        float pv[4];
#pragma unroll
        for (int r = 0; r < 4; ++r) {
          int i = kb * 4 + r;
          float bmf = bf2f((u16)bmv[s][i >> 3][i & 7]);
          pv[r] = fast_exp2(S[s][kb][r] + bmf);
        }
        int seg = kb * 2 + (l15 >> 3);
#pragma unroll
        for (int r = 0; r < 4; r += 2) {
          union { __hip_bfloat162 h; u16 u[2]; } cv;
          cv.h = __float22bfloat162_rn(make_float2(pv[r], pv[r + 1]));
          int row0 = quad * 4 + r, row1 = row0 + 1;
          ps[row0 * 128 + ((seg ^ row0) & 15) * 8 + (l15 & 7)] = cv.u[0];
          ps[row1 * 128 + ((seg ^ row1) & 15) * 8 + (l15 & 7)] = cv.u[1];
        }
      }
      // same-wave DS ops are in-order: reads below see the writes above
#pragma unroll
      for (int m = 0; m < 4; ++m) {
        int seg = m * 4 + quad;
        pa[s][m] = *(const short8*)&Ps[wave][l15 * 128 + ((seg ^ l15) & 15) * 8];
      }
    }

    // ---- O += P.V ; denominator via P.ones column ----
#pragma unroll
    for (int nb = 0; nb < 4; ++nb) {
      int vrow = nb * 16 + l15;
#pragma unroll
      for (int m = 0; m < 4; ++m) {
        int seg = m * 4 + quad;
        short8 vb = *(const short8*)&Vs[cur][vrow * 128 + ((seg ^ (vrow & 15)) & 15) * 8];
        O[0][nb] = MFMA16(pa[0][m], vb, O[0][nb]);
        O[1][nb] = MFMA16(pa[1][m], vb, O[1][nb]);
      }
    }
#pragma unroll
    for (int s = 0; s < 2; ++s)
#pragma unroll
      for (int m = 0; m < 4; ++m) O5[s] = MFMA16(pa[s][m], bones, O5[s]);
  }

#pragma unroll
  for (int s = 0; s < 2; ++s)
#pragma unroll
    for (int r = 0; r < 4; ++r) {
      float l = O5[s][r];
      float inv = l > 0.f ? 1.f / l : 0.f;
      int qd = qbase + s * 16 + quad * 4 + r;
      u16* cp = ctx + (size_t)(b * 1024 + qd) * 512 + h * 64;
#pragma unroll
      for (int nb = 0; nb < 4; ++nb) cp[nb * 16 + l15] = f2bf(O[s][nb][r] * inv);
    }
}

extern "C" void kernel_launch(void* const* d_in, const int* in_sizes, int n_in,
                              void* d_out, int out_size, void* d_ws, size_t ws_size,
                              hipStream_t stream) {
  const float* u_enc = (const float*)d_in[0];
  const float* e_enc = (const float*)d_in[1];
  const float* logit_bpp = (const float*)d_in[2];
  const int* ue_mask = (const int*)d_in[3];
  const int* eu_mask = (const int*)d_in[4];
  const float* wq_k = (const float*)d_in[5];
  const float* wq_b = (const float*)d_in[6];
  const float* wk_k = (const float*)d_in[7];
  const float* wk_b = (const float*)d_in[8];
  const float* wv_k = (const float*)d_in[9];
  const float* wv_b = (const float*)d_in[10];
  const float* wo_k = (const float*)d_in[11];
  const float* wo_b = (const float*)d_in[12];
  const float* bpp_w = (const float*)d_in[13];
  const float* bpp_b = (const float*)d_in[14];

  float* out = (float*)d_out;

  // ws layout (u16 units); total ~65 MB (R1 proved ws >= 67 MB)
  u16* ws16 = (u16*)d_ws;
  u16* ab    = ws16;                    // 4,194,304  (8192x512 bf16 inputs)
  u16* Wt    = ab + 4194304;            // 1,048,576  (4x 512x512 transposed)
  u16* q_all = Wt + 1048576;            // 4,194,304
  u16* k_all = q_all + 4194304;         // 4,194,304
  u16* v_all = k_all + 4194304;         // 4,194,304
  u16* ctx   = v_all + 4194304;         // 4,194,304
  u16* bm    = ctx + 4194304;           // 8,388,608  (2 sides x 4M)
  float* bppT = (float*)(bm + 8388608); // 1,048,576 f32
  float* bias_all = bppT + 1048576;     // 2048 f32
  u16* vt = ab;                         // alias: ab dead after gemm<0>

  cvt_bf16<<<dim3(2048, 2), 256, 0, stream>>>(u_enc, e_enc, ab);
  wtrans<<<dim3(16, 16, 4), 256, 0, stream>>>(wq_k, wk_k, wv_k, wo_k, Wt);
  bias_cat<<<8, 256, 0, stream>>>(wq_b, wk_b, wv_b, wo_b, bias_all);
  bpp_t<<<dim3(32, 32), 256, 0, stream>>>(logit_bpp, bppT);
  build_bm<<<dim3(8, 16, 8), 256, 0, stream>>>(ue_mask, eu_mask, logit_bpp, bppT,
                                               bpp_w, bpp_b, bm);

  gemm_mfma<0><<<dim3(64, 12), 256, 0, stream>>>(ab, Wt, bias_all, nullptr,
                                                 q_all, k_all, v_all);
  vt_trans<<<dim3(16, 8, 8), 256, 0, stream>>>(v_all, vt);
  attn_mfma<<<dim3(8, 8, 8), 256, 0, stream>>>(q_all, k_all, vt, bm, ctx);
  gemm_mfma<1><<<dim3(64, 4), 256, 0, stream>>>(ctx, Wt + 786432, bias_all + 1536,
                                                out, nullptr, nullptr, nullptr);
}

// Round 4
// 203.426 us; speedup vs baseline: 10.6821x; 1.0865x over previous
//
#include <hip/hip_runtime.h>
#include <hip/hip_bf16.h>
#include <cstdint>

typedef unsigned short u16;
typedef __attribute__((ext_vector_type(8))) short short8;
typedef __attribute__((ext_vector_type(4))) float floatx4;

#define MFMA16(a, b, c) __builtin_amdgcn_mfma_f32_16x16x32_bf16(a, b, c, 0, 0, 0)
#define LOG2E 1.4426950408889634f

__device__ __forceinline__ float fast_exp2(float x) {
#if __has_builtin(__builtin_amdgcn_exp2f)
  return __builtin_amdgcn_exp2f(x);
#else
  return exp2f(x);
#endif
}
__device__ __forceinline__ u16 f2bf(float v) {
  union { float f; unsigned u; } x; x.f = v;
  unsigned r = x.u + 0x7FFF + ((x.u >> 16) & 1);  // RNE
  return (u16)(r >> 16);
}
__device__ __forceinline__ float bf2f(u16 v) {
  union { unsigned u; float f; } x; x.u = ((unsigned)v) << 16; return x.f;
}
__device__ __forceinline__ void gload_lds16(const u16* g, u16* l) {
  __builtin_amdgcn_global_load_lds(
      (const __attribute__((address_space(1))) unsigned int*)(g),
      (__attribute__((address_space(3))) unsigned int*)(l), 16, 0, 0);
}

// ---------- fused prep: cvt(u,e) | wtrans x4 | bpp_t | bias_cat ----------
// blocks [0,4096): cvt; [4096,5120): wtrans; [5120,6144): bpp_t; [6144,6152): bias
__global__ __launch_bounds__(256) void prep(
    const float* __restrict__ u, const float* __restrict__ e,
    const float* __restrict__ wq, const float* __restrict__ wk,
    const float* __restrict__ wv, const float* __restrict__ wo,
    const float* __restrict__ bq, const float* __restrict__ bk,
    const float* __restrict__ bv, const float* __restrict__ bo,
    const float* __restrict__ bpp,
    u16* __restrict__ ab, u16* __restrict__ Wt,
    float* __restrict__ bppT, float* __restrict__ bias_all) {
  __shared__ float tl[32][33];
  const int bid = blockIdx.x, t = threadIdx.x;
  if (bid < 4096) {
    int half = bid >> 11;
    int i = ((bid & 2047) * 256 + t) * 4;
    const float* s = half ? e : u;
    float4 v = *(const float4*)(s + i);
    ushort4 o = make_ushort4(f2bf(v.x), f2bf(v.y), f2bf(v.z), f2bf(v.w));
    *(ushort4*)(ab + (size_t)half * 2097152 + i) = o;
  } else if (bid < 5120) {
    int i = bid - 4096;
    int z = i >> 8, rem = i & 255;
    const float* src = z == 0 ? wq : z == 1 ? wk : z == 2 ? wv : wo;
    float scale = z == 0 ? 0.125f * LOG2E : 1.0f;
    u16* dst = Wt + (size_t)z * 262144;
    int k0 = (rem & 15) * 32, n0 = (rem >> 4) * 32;
    int tx = t & 31, ty = t >> 5;
#pragma unroll
    for (int j = 0; j < 32; j += 8) tl[ty + j][tx] = src[(size_t)(k0 + ty + j) * 512 + n0 + tx];
    __syncthreads();
#pragma unroll
    for (int j = 0; j < 32; j += 8)
      dst[(size_t)(n0 + ty + j) * 512 + k0 + tx] = f2bf(scale * tl[tx][ty + j]);
  } else if (bid < 6144) {
    int i = bid - 5120;
    int a0 = (i & 31) * 32, b0 = (i >> 5) * 32;
    int tx = t & 31, ty = t >> 5;
#pragma unroll
    for (int j = 0; j < 32; j += 8) tl[ty + j][tx] = bpp[(size_t)(b0 + ty + j) * 1024 + a0 + tx];
    __syncthreads();
#pragma unroll
    for (int j = 0; j < 32; j += 8) bppT[(size_t)(a0 + ty + j) * 1024 + b0 + tx] = tl[tx][ty + j];
  } else {
    int n = (bid - 6144) * 256 + t;  // 0..2047
    float val = n < 512 ? 0.125f * LOG2E * bq[n]
              : n < 1024 ? bk[n - 512]
              : n < 1536 ? bv[n - 1024] : bo[n - 1536];
    bias_all[n] = val;
  }
}

// ---------- bias-mask, MFMA C-fragment layout, 64-key chunks, log2e folded ----------
// bm[side][b][q16][kc][lane][i]; i=kb*4+r -> (q=q16*16+quad*4+r, k=kc*64+kb*16+l15)
__global__ __launch_bounds__(256) void build_bm(
    const int* __restrict__ mu, const int* __restrict__ me,
    const float* __restrict__ bpp, const float* __restrict__ bppT,
    const float* __restrict__ bw_p, const float* __restrict__ bb_p,
    u16* __restrict__ bm) {
  __shared__ u16 lds[2048];
  const int kcpair = blockIdx.x, q16 = blockIdx.y;
  const int side = blockIdx.z >> 2, b = blockIdx.z & 3;
  const int* mask = side ? me : mu;
  const float* bp = side ? bppT : bpp;
  const float sw = (*bw_p) * LOG2E, sb = (*bb_p) * LOG2E;
  const int t = threadIdx.x;
#pragma unroll
  for (int ii = 0; ii < 2; ++ii) {
    int s = t + ii * 256;
    int q = s >> 5;            // 0..15
    int kq = (s & 31) * 4;     // 0..124
    int qg = q16 * 16 + q, kg = kcpair * 128 + kq;
    int4 mv = *(const int4*)(mask + ((size_t)b * 1024 + qg) * 1024 + kg);
    float4 bv = *(const float4*)(bp + (size_t)qg * 1024 + kg);
    int kb = (kq >> 4) & 3, kc_loc = kq >> 6;
    int quad = q >> 2, r = q & 3;
    u16 o[4];
    o[0] = f2bf(mv.x ? sw * bv.x + sb : -1e30f);
    o[1] = f2bf(mv.y ? sw * bv.y + sb : -1e30f);
    o[2] = f2bf(mv.z ? sw * bv.z + sb : -1e30f);
    o[3] = f2bf(mv.w ? sw * bv.w + sb : -1e30f);
#pragma unroll
    for (int j = 0; j < 4; ++j) {
      int l15 = (kq & 15) + j;
      lds[kc_loc * 1024 + (quad * 16 + l15) * 16 + kb * 4 + r] = o[j];
    }
  }
  __syncthreads();
  u16* dst = bm + ((((size_t)side * 4 + b) * 64 + q16) * 16 + kcpair * 2) * 1024;
  *(short8*)(dst + t * 8) = *(const short8*)&lds[t * 8];
}

// ---------- MFMA GEMM (m97 structure) ----------
// MODE 0: N=1536 -> q/k/v bf16; MODE 1: N=512 -> fp32 out
template <int MODE>
__global__ __launch_bounds__(256) void gemm_mfma(
    const u16* __restrict__ A, const u16* __restrict__ Bt,
    const float* __restrict__ bias, float* __restrict__ outf,
    u16* __restrict__ q_o, u16* __restrict__ k_o, u16* __restrict__ v_o) {
  __shared__ u16 As[128 * 32];
  __shared__ u16 Bs[128 * 32];
  const int t = threadIdx.x, lane = t & 63, wave = t >> 6;
  const int l15 = lane & 15, quad = lane >> 4;
  const int wy = wave >> 1, wx = wave & 1;
  const int m0 = blockIdx.x * 128, n0 = blockIdx.y * 128;
  const int K = 512;

  floatx4 zero4 = {0.f, 0.f, 0.f, 0.f};
  floatx4 acc[4][4];
#pragma unroll
  for (int mi = 0; mi < 4; ++mi)
#pragma unroll
    for (int ni = 0; ni < 4; ++ni) acc[mi][ni] = zero4;

  for (int k0 = 0; k0 < K; k0 += 32) {
    __syncthreads();
    {
      int s = t;
#pragma unroll
      for (int i = 0; i < 2; ++i, s += 256) {
        int row = s >> 2, seg = s & 3;
        gload_lds16(A + (size_t)(m0 + row) * K + k0 + seg * 8, &As[s * 8]);
      }
      s = t;
#pragma unroll
      for (int i = 0; i < 2; ++i, s += 256) {
        int row = s >> 2, seg = s & 3;
        gload_lds16(Bt + (size_t)(n0 + row) * K + k0 + seg * 8, &Bs[s * 8]);
      }
    }
    __syncthreads();
    short8 af[4], bf[4];
#pragma unroll
    for (int mi = 0; mi < 4; ++mi)
      af[mi] = *(const short8*)&As[(wy * 64 + mi * 16 + l15) * 32 + quad * 8];
#pragma unroll
    for (int ni = 0; ni < 4; ++ni)
      bf[ni] = *(const short8*)&Bs[(wx * 64 + ni * 16 + l15) * 32 + quad * 8];
#pragma unroll
    for (int mi = 0; mi < 4; ++mi)
#pragma unroll
      for (int ni = 0; ni < 4; ++ni) acc[mi][ni] = MFMA16(af[mi], bf[ni], acc[mi][ni]);
  }

#pragma unroll
  for (int mi = 0; mi < 4; ++mi)
#pragma unroll
    for (int ni = 0; ni < 4; ++ni) {
      int n = n0 + wx * 64 + ni * 16 + l15;
      float bv = bias[n];
#pragma unroll
      for (int r = 0; r < 4; ++r) {
        int m = m0 + wy * 64 + mi * 16 + quad * 4 + r;
        float v = acc[mi][ni][r] + bv;
        if (MODE == 1) {
          outf[(size_t)m * 512 + n] = v;
        } else {
          int sel = n >> 9, c = n & 511;  // block-uniform
          u16 hv = f2bf(v);
          if (sel == 0) q_o[(size_t)m * 512 + c] = hv;
          else if (sel == 1) k_o[(size_t)m * 512 + c] = hv;
          else v_o[(size_t)m * 512 + c] = hv;
        }
      }
    }
}

// ---------- v [m][h*64+hd] -> vt [half][b][h][hd][l] ----------
__global__ __launch_bounds__(256) void vt_trans(const u16* __restrict__ v_all,
                                                u16* __restrict__ vt_all) {
  __shared__ u16 tl[64][72];
  int z = blockIdx.z, half = z >> 2, b = z & 3, h = blockIdx.y, l0 = blockIdx.x * 64;
  const u16* src = v_all + (size_t)half * 2097152;
  u16* dst = vt_all + (size_t)half * 2097152;
  int t = threadIdx.x;
#pragma unroll
  for (int i = 0; i < 2; ++i) {
    int s = t + i * 256, row = s >> 3, seg = s & 7;
    *(short8*)&tl[row][seg * 8] =
        *(const short8*)(src + (size_t)(b * 1024 + l0 + row) * 512 + h * 64 + seg * 8);
  }
  __syncthreads();
#pragma unroll
  for (int i = 0; i < 2; ++i) {
    int s = t + i * 256, hd = s >> 3, seg = s & 7;
    u16 tmp[8];
#pragma unroll
    for (int j = 0; j < 8; ++j) tmp[j] = tl[seg * 8 + j][hd];
    *(short8*)(dst + ((size_t)(b * 8 + h) * 64 + hd) * 1024 + l0 + seg * 8) =
        *(const short8*)tmp;
  }
}

// ---------- MFMA flash attention: 64q blocks, 64-key chunks, 4 blocks/CU ----------
__global__ __launch_bounds__(256, 4) void attn_mfma(
    const u16* __restrict__ q_all, const u16* __restrict__ k_all,
    const u16* __restrict__ vt_all, const u16* __restrict__ bm_all,
    u16* __restrict__ ctx_all) {
  __shared__ u16 Ks[2][64 * 64];   // 8 KB x2
  __shared__ u16 Vs[2][64 * 64];   // 8 KB x2
  __shared__ u16 Ps[4][16 * 64];   // 2 KB/wave
  const int t = threadIdx.x, lane = t & 63, wave = t >> 6;
  const int l15 = lane & 15, quad = lane >> 4;

  // XCD-clustering decode: sharers of one (side,b,h) K/V land on one XCD
  const int f = blockIdx.x;
  const int g = f & 7, r0 = f >> 3;
  const int combo = g * 8 + (r0 >> 4);  // 0..63
  const int x = r0 & 15;                // q-block 0..15
  const int side = combo >> 5, b = (combo >> 3) & 3, h = combo & 7;

  const size_t HALF = 2097152;
  const u16* Q = q_all + side * HALF;
  const u16* K = k_all + (1 - side) * HALF;
  const u16* Vt = vt_all + (1 - side) * HALF;
  const u16* bm = bm_all + side * (size_t)4194304;
  u16* ctx = ctx_all + side * HALF;
  const int qbase = x * 64 + wave * 16;
  const int q16g = qbase >> 4;

  short8 qa0, qa1;
  {
    const u16* qp = Q + (size_t)(b * 1024 + qbase + l15) * 512 + h * 64 + quad * 8;
    qa0 = *(const short8*)qp;
    qa1 = *(const short8*)(qp + 32);
  }

  short8 bones;
#pragma unroll
  for (int j = 0; j < 8; ++j) bones[j] = (short)0x3F80;

  floatx4 O[4], O5;
  O5 = (floatx4){0.f, 0.f, 0.f, 0.f};
#pragma unroll
  for (int nb = 0; nb < 4; ++nb) O[nb] = (floatx4){0.f, 0.f, 0.f, 0.f};

#define STAGE(buf, k0)                                                             \
  {                                                                                \
    _Pragma("unroll") for (int i = 0; i < 2; ++i) {                                \
      int s = t + i * 256, row = s >> 3, pseg = s & 7, lseg = pseg ^ (row & 7);    \
      gload_lds16(K + (size_t)(b * 1024 + (k0) + row) * 512 + h * 64 + lseg * 8,   \
                  &Ks[buf][s * 8]);                                                \
      gload_lds16(Vt + ((size_t)(b * 8 + h) * 64 + row) * 1024 + (k0) + lseg * 8,  \
                  &Vs[buf][s * 8]);                                                \
    }                                                                              \
  }

  STAGE(0, 0)

  for (int it = 0; it < 16; ++it) {
    const int cur = it & 1;
    __syncthreads();
    if (it < 15) STAGE(cur ^ 1, it * 64 + 64)

    // bm fragment (C-layout): 16 u16 per lane
    short8 bmv0, bmv1;
    {
      const u16* bp = bm + ((((size_t)b * 64 + q16g) * 16 + it) * 64 + lane) * 16;
      bmv0 = *(const short8*)bp;
      bmv1 = *(const short8*)(bp + 8);
    }

    // ---- S = Q.K^T - 64 ----
    floatx4 S[4];
#pragma unroll
    for (int kb = 0; kb < 4; ++kb) S[kb] = (floatx4){-64.f, -64.f, -64.f, -64.f};
#pragma unroll
    for (int kb = 0; kb < 4; ++kb) {
      int krow = kb * 16 + l15;
      short8 b0 = *(const short8*)&Ks[cur][krow * 64 + ((quad ^ (krow & 7)) * 8)];
      short8 b1 = *(const short8*)&Ks[cur][krow * 64 + (((4 + quad) ^ (krow & 7)) * 8)];
      S[kb] = MFMA16(qa0, b0, S[kb]);
      S[kb] = MFMA16(qa1, b1, S[kb]);
    }

    // ---- p = exp2(S + bm); masked bm=-1e30 -> exact 0 ----
    u16* ps = &Ps[wave][0];
#pragma unroll
    for (int kb = 0; kb < 4; ++kb) {
      float pv[4];
#pragma unroll
      for (int r = 0; r < 4; ++r) {
        int i = kb * 4 + r;
        float bmf = bf2f((u16)((i < 8) ? bmv0[i] : bmv1[i - 8]));
        pv[r] = fast_exp2(S[kb][r] + bmf);
      }
      int seg = kb * 2 + (l15 >> 3);
#pragma unroll
      for (int r = 0; r < 4; r += 2) {
        union { __hip_bfloat162 hh; u16 u[2]; } cv;
        cv.hh = __float22bfloat162_rn(make_float2(pv[r], pv[r + 1]));
        int row0 = quad * 4 + r, row1 = row0 + 1;
        ps[row0 * 64 + ((seg ^ (row0 & 7)) * 8) + (l15 & 7)] = cv.u[0];
        ps[row1 * 64 + ((seg ^ (row1 & 7)) * 8) + (l15 & 7)] = cv.u[1];
      }
    }
    // same-wave DS ops are in-order
    short8 pa0 = *(const short8*)&ps[l15 * 64 + ((quad ^ (l15 & 7)) * 8)];
    short8 pa1 = *(const short8*)&ps[l15 * 64 + (((4 + quad) ^ (l15 & 7)) * 8)];

    // ---- O += P.V ; denom via P.ones ----
#pragma unroll
    for (int nb = 0; nb < 4; ++nb) {
      int vrow = nb * 16 + l15;
      short8 v0 = *(const short8*)&Vs[cur][vrow * 64 + ((quad ^ (vrow & 7)) * 8)];
      short8 v1 = *(const short8*)&Vs[cur][vrow * 64 + (((4 + quad) ^ (vrow & 7)) * 8)];
      O[nb] = MFMA16(pa0, v0, O[nb]);
      O[nb] = MFMA16(pa1, v1, O[nb]);
    }
    O5 = MFMA16(pa0, bones, O5);
    O5 = MFMA16(pa1, bones, O5);
  }

#pragma unroll
  for (int r = 0; r < 4; ++r) {
    float l = O5[r];
    float inv = l > 0.f ? 1.f / l : 0.f;
    int qd = qbase + quad * 4 + r;
    u16* cp = ctx + (size_t)(b * 1024 + qd) * 512 + h * 64;
#pragma unroll
    for (int nb = 0; nb < 4; ++nb) cp[nb * 16 + l15] = f2bf(O[nb][r] * inv);
  }
}

extern "C" void kernel_launch(void* const* d_in, const int* in_sizes, int n_in,
                              void* d_out, int out_size, void* d_ws, size_t ws_size,
                              hipStream_t stream) {
  const float* u_enc = (const float*)d_in[0];
  const float* e_enc = (const float*)d_in[1];
  const float* logit_bpp = (const float*)d_in[2];
  const int* ue_mask = (const int*)d_in[3];
  const int* eu_mask = (const int*)d_in[4];
  const float* wq_k = (const float*)d_in[5];
  const float* wq_b = (const float*)d_in[6];
  const float* wk_k = (const float*)d_in[7];
  const float* wk_b = (const float*)d_in[8];
  const float* wv_k = (const float*)d_in[9];
  const float* wv_b = (const float*)d_in[10];
  const float* wo_k = (const float*)d_in[11];
  const float* wo_b = (const float*)d_in[12];
  const float* bpp_w = (const float*)d_in[13];
  const float* bpp_b = (const float*)d_in[14];

  float* out = (float*)d_out;

  u16* ws16 = (u16*)d_ws;
  u16* ab    = ws16;                     // 4,194,304 u16
  u16* Wt    = ab + 4194304;             // 1,048,576
  u16* q_all = Wt + 1048576;             // 4,194,304
  u16* k_all = q_all + 4194304;          // 4,194,304
  u16* v_all = k_all + 4194304;          // 4,194,304
  u16* ctx   = v_all + 4194304;          // 4,194,304
  u16* bm    = ctx + 4194304;            // 8,388,608
  float* bppT = (float*)(bm + 8388608);  // 1,048,576 f32
  float* bias_all = bppT + 1048576;      // 2048 f32
  u16* vt = ab;                          // alias: ab dead after gemm<0>

  prep<<<6152, 256, 0, stream>>>(u_enc, e_enc, wq_k, wk_k, wv_k, wo_k,
                                 wq_b, wk_b, wv_b, wo_b, logit_bpp,
                                 ab, Wt, bppT, bias_all);
  build_bm<<<dim3(8, 64, 8), 256, 0, stream>>>(ue_mask, eu_mask, logit_bpp, bppT,
                                               bpp_w, bpp_b, bm);
  gemm_mfma<0><<<dim3(64, 12), 256, 0, stream>>>(ab, Wt, bias_all, nullptr,
                                                 q_all, k_all, v_all);
  vt_trans<<<dim3(16, 8, 8), 256, 0, stream>>>(v_all, vt);
  attn_mfma<<<1024, 256, 0, stream>>>(q_all, k_all, vt, bm, ctx);
  gemm_mfma<1><<<dim3(64, 4), 256, 0, stream>>>(ctx, Wt + 786432, bias_all + 1536,
                                                out, nullptr, nullptr, nullptr);
}

// Round 5
// 197.287 us; speedup vs baseline: 11.0145x; 1.0311x over previous
//
#include <hip/hip_runtime.h>
#include <hip/hip_bf16.h>
#include <cstdint>

typedef unsigned short u16;
typedef __attribute__((ext_vector_type(8))) short short8;
typedef __attribute__((ext_vector_type(4))) float floatx4;

#define MFMA16(a, b, c) __builtin_amdgcn_mfma_f32_16x16x32_bf16(a, b, c, 0, 0, 0)
#define LOG2E 1.4426950408889634f

__device__ __forceinline__ float fast_exp2(float x) {
#if __has_builtin(__builtin_amdgcn_exp2f)
  return __builtin_amdgcn_exp2f(x);
#else
  return exp2f(x);
#endif
}
__device__ __forceinline__ u16 f2bf(float v) {
  union { float f; unsigned u; } x; x.f = v;
  unsigned r = x.u + 0x7FFF + ((x.u >> 16) & 1);  // RNE
  return (u16)(r >> 16);
}
__device__ __forceinline__ float bf2f(u16 v) {
  union { unsigned u; float f; } x; x.u = ((unsigned)v) << 16; return x.f;
}
__device__ __forceinline__ void gload_lds16(const u16* g, u16* l) {
  __builtin_amdgcn_global_load_lds(
      (const __attribute__((address_space(1))) unsigned int*)(g),
      (__attribute__((address_space(3))) unsigned int*)(l), 16, 0, 0);
}

// permlane swaps (gfx950). Semantics:
// pl32swap: X'[lo]=X[lo], X'[hi]=Y[lo]; Y'[lo]=X[hi], Y'[hi]=Y[hi]
// pl16swap: X'[even16]=X[even16], X'[odd16]=Y[even16]; Y'[even16]=X[odd16], Y'[odd16]=Y[odd16]
#if __has_builtin(__builtin_amdgcn_permlane32_swap) && __has_builtin(__builtin_amdgcn_permlane16_swap)
#define HAVE_PL 1
#endif
__device__ __forceinline__ void plswap32(unsigned& x, unsigned& y) {
#ifdef HAVE_PL
  auto r = __builtin_amdgcn_permlane32_swap(x, y, false, false);
  x = r[0]; y = r[1];
#else
  unsigned sx = (unsigned)__shfl_xor((int)x, 32, 64);
  unsigned sy = (unsigned)__shfl_xor((int)y, 32, 64);
  bool hi = (threadIdx.x & 32) != 0;
  unsigned nx = hi ? sy : x;
  unsigned ny = hi ? y : sx;
  x = nx; y = ny;
#endif
}
__device__ __forceinline__ void plswap16(unsigned& x, unsigned& y) {
#ifdef HAVE_PL
  auto r = __builtin_amdgcn_permlane16_swap(x, y, false, false);
  x = r[0]; y = r[1];
#else
  unsigned sx = (unsigned)__shfl_xor((int)x, 16, 64);
  unsigned sy = (unsigned)__shfl_xor((int)y, 16, 64);
  bool odd = (threadIdx.x & 16) != 0;
  unsigned nx = odd ? sy : x;
  unsigned ny = odd ? y : sx;
  x = nx; y = ny;
#endif
}

// ---------- mega-prep: cvt | wtrans | bias_cat | build_bm ----------
// [0,4096): cvt u/e; [4096,5120): wtrans; [5120,5128): bias; [5128,9224): build_bm
__global__ __launch_bounds__(256) void prep(
    const float* __restrict__ u, const float* __restrict__ e,
    const float* __restrict__ wq, const float* __restrict__ wk,
    const float* __restrict__ wv, const float* __restrict__ wo,
    const float* __restrict__ bq, const float* __restrict__ bk,
    const float* __restrict__ bv, const float* __restrict__ bo,
    const float* __restrict__ bpp,
    const int* __restrict__ mu, const int* __restrict__ me,
    const float* __restrict__ bw_p, const float* __restrict__ bb_p,
    u16* __restrict__ ab, u16* __restrict__ Wt,
    float* __restrict__ bias_all, u16* __restrict__ bm) {
  __shared__ float smemf[2176];   // wtrans tile (32x33) / bppT stage (128x17)
  __shared__ u16 smemo[2048];     // build_bm output stage
  const int bid = blockIdx.x, t = threadIdx.x;
  if (bid < 4096) {
    int half = bid >> 11;
    int i = ((bid & 2047) * 256 + t) * 4;
    const float* s = half ? e : u;
    float4 v = *(const float4*)(s + i);
    ushort4 o = make_ushort4(f2bf(v.x), f2bf(v.y), f2bf(v.z), f2bf(v.w));
    *(ushort4*)(ab + (size_t)half * 2097152 + i) = o;
  } else if (bid < 5120) {
    int i = bid - 4096;
    int z = i >> 8, rem = i & 255;
    const float* src = z == 0 ? wq : z == 1 ? wk : z == 2 ? wv : wo;
    float scale = z == 0 ? 0.125f * LOG2E : 1.0f;
    u16* dst = Wt + (size_t)z * 262144;
    int k0 = (rem & 15) * 32, n0 = (rem >> 4) * 32;
    int tx = t & 31, ty = t >> 5;
    float (*tl)[33] = (float(*)[33])smemf;
#pragma unroll
    for (int j = 0; j < 32; j += 8) tl[ty + j][tx] = src[(size_t)(k0 + ty + j) * 512 + n0 + tx];
    __syncthreads();
#pragma unroll
    for (int j = 0; j < 32; j += 8)
      dst[(size_t)(n0 + ty + j) * 512 + k0 + tx] = f2bf(scale * tl[tx][ty + j]);
  } else if (bid < 5128) {
    int n = (bid - 5120) * 256 + t;  // 0..2047
    float val = n < 512 ? 0.125f * LOG2E * bq[n]
              : n < 1024 ? bk[n - 512]
              : n < 1536 ? bv[n - 1024] : bo[n - 1536];
    bias_all[n] = val;
  } else {
    // build_bm: bm[sb][q16][chunk16][lane][i]; lane=(q=l15,quad), i=kb*4+r
    // value(q,k): k = chunk*64 + kb*16 + quad*4 + r
    int i = bid - 5128;
    int kcpair = i & 7, q16 = (i >> 3) & 63, sb = i >> 9;  // sb = side*4+b
    int side = sb >> 2, b = sb & 3;
    const int* mask = side ? me : mu;
    const float sw = (*bw_p) * LOG2E, sb2 = (*bb_p) * LOG2E;
    if (side) {  // stage bpp^T tile: smemf[k_loc][q_loc], k_loc<128, stride 17
#pragma unroll
      for (int ii = 0; ii < 2; ++ii) {
        int s = t + ii * 256;
        int rowk = s >> 2, c4 = (s & 3) * 4;
        float4 v = *(const float4*)(bpp + (size_t)(kcpair * 128 + rowk) * 1024 + q16 * 16 + c4);
        smemf[rowk * 17 + c4 + 0] = v.x;
        smemf[rowk * 17 + c4 + 1] = v.y;
        smemf[rowk * 17 + c4 + 2] = v.z;
        smemf[rowk * 17 + c4 + 3] = v.w;
      }
    }
    __syncthreads();
#pragma unroll
    for (int ii = 0; ii < 2; ++ii) {
      int s = t + ii * 256;
      int q_loc = s >> 5;        // 0..15
      int kq = (s & 31) * 4;     // 0..124
      int qg = q16 * 16 + q_loc;
      int4 mv = *(const int4*)(mask + ((size_t)b * 1024 + qg) * 1024 + kcpair * 128 + kq);
      float bvv[4];
      if (side) {
#pragma unroll
        for (int j = 0; j < 4; ++j) bvv[j] = smemf[(kq + j) * 17 + q_loc];
      } else {
        float4 v = *(const float4*)(bpp + (size_t)qg * 1024 + kcpair * 128 + kq);
        bvv[0] = v.x; bvv[1] = v.y; bvv[2] = v.z; bvv[3] = v.w;
      }
      int mm[4] = {mv.x, mv.y, mv.z, mv.w};
      int kc_loc = kq >> 6, k_loc = kq & 63;
      int kb = k_loc >> 4, within = k_loc & 15;
      int quad = within >> 2;
      int lane = q_loc + 16 * quad;
      u16 o[4];
#pragma unroll
      for (int j = 0; j < 4; ++j) o[j] = f2bf(mm[j] ? sw * bvv[j] + sb2 : -1e30f);
      *(ushort4*)&smemo[kc_loc * 1024 + lane * 16 + kb * 4] = *(const ushort4*)o;
    }
    __syncthreads();
    u16* dst = bm + (((size_t)sb * 64 + q16) * 16 + kcpair * 2) * 1024;
    *(short8*)(dst + t * 8) = *(const short8*)&smemo[t * 8];
  }
}

// ---------- MFMA GEMM (m97 structure) ----------
template <int MODE>
__global__ __launch_bounds__(256) void gemm_mfma(
    const u16* __restrict__ A, const u16* __restrict__ Bt,
    const float* __restrict__ bias, float* __restrict__ outf,
    u16* __restrict__ q_o, u16* __restrict__ k_o, u16* __restrict__ v_o) {
  __shared__ u16 As[128 * 32];
  __shared__ u16 Bs[128 * 32];
  const int t = threadIdx.x, lane = t & 63, wave = t >> 6;
  const int l15 = lane & 15, quad = lane >> 4;
  const int wy = wave >> 1, wx = wave & 1;
  const int m0 = blockIdx.x * 128, n0 = blockIdx.y * 128;
  const int K = 512;

  floatx4 zero4 = {0.f, 0.f, 0.f, 0.f};
  floatx4 acc[4][4];
#pragma unroll
  for (int mi = 0; mi < 4; ++mi)
#pragma unroll
    for (int ni = 0; ni < 4; ++ni) acc[mi][ni] = zero4;

  for (int k0 = 0; k0 < K; k0 += 32) {
    __syncthreads();
    {
      int s = t;
#pragma unroll
      for (int i = 0; i < 2; ++i, s += 256) {
        int row = s >> 2, seg = s & 3;
        gload_lds16(A + (size_t)(m0 + row) * K + k0 + seg * 8, &As[s * 8]);
      }
      s = t;
#pragma unroll
      for (int i = 0; i < 2; ++i, s += 256) {
        int row = s >> 2, seg = s & 3;
        gload_lds16(Bt + (size_t)(n0 + row) * K + k0 + seg * 8, &Bs[s * 8]);
      }
    }
    __syncthreads();
    short8 af[4], bf[4];
#pragma unroll
    for (int mi = 0; mi < 4; ++mi)
      af[mi] = *(const short8*)&As[(wy * 64 + mi * 16 + l15) * 32 + quad * 8];
#pragma unroll
    for (int ni = 0; ni < 4; ++ni)
      bf[ni] = *(const short8*)&Bs[(wx * 64 + ni * 16 + l15) * 32 + quad * 8];
#pragma unroll
    for (int mi = 0; mi < 4; ++mi)
#pragma unroll
      for (int ni = 0; ni < 4; ++ni) acc[mi][ni] = MFMA16(af[mi], bf[ni], acc[mi][ni]);
  }

#pragma unroll
  for (int mi = 0; mi < 4; ++mi)
#pragma unroll
    for (int ni = 0; ni < 4; ++ni) {
      int n = n0 + wx * 64 + ni * 16 + l15;
      float bv = bias[n];
#pragma unroll
      for (int r = 0; r < 4; ++r) {
        int m = m0 + wy * 64 + mi * 16 + quad * 4 + r;
        float v = acc[mi][ni][r] + bv;
        if (MODE == 1) {
          outf[(size_t)m * 512 + n] = v;
        } else {
          int sel = n >> 9, c = n & 511;  // block-uniform
          u16 hv = f2bf(v);
          if (sel == 0) q_o[(size_t)m * 512 + c] = hv;
          else if (sel == 1) k_o[(size_t)m * 512 + c] = hv;
          else v_o[(size_t)m * 512 + c] = hv;
        }
      }
    }
}

// ---------- v [m][h*64+hd] -> vt [half][b][h][hd][l] ----------
__global__ __launch_bounds__(256) void vt_trans(const u16* __restrict__ v_all,
                                                u16* __restrict__ vt_all) {
  __shared__ u16 tl[64][72];
  int z = blockIdx.z, half = z >> 2, b = z & 3, h = blockIdx.y, l0 = blockIdx.x * 64;
  const u16* src = v_all + (size_t)half * 2097152;
  u16* dst = vt_all + (size_t)half * 2097152;
  int t = threadIdx.x;
#pragma unroll
  for (int i = 0; i < 2; ++i) {
    int s = t + i * 256, row = s >> 3, seg = s & 7;
    *(short8*)&tl[row][seg * 8] =
        *(const short8*)(src + (size_t)(b * 1024 + l0 + row) * 512 + h * 64 + seg * 8);
  }
  __syncthreads();
#pragma unroll
  for (int i = 0; i < 2; ++i) {
    int s = t + i * 256, hd = s >> 3, seg = s & 7;
    u16 tmp[8];
#pragma unroll
    for (int j = 0; j < 8; ++j) tmp[j] = tl[seg * 8 + j][hd];
    *(short8*)(dst + ((size_t)(b * 8 + h) * 64 + hd) * 1024 + l0 + seg * 8) =
        *(const short8*)tmp;
  }
}

// ---------- MFMA flash attention v2: S^T + in-register P^T, no LDS round-trip ----------
// 128 q/block, 32 q/wave, 64-key chunks, dbuf staging
__global__ __launch_bounds__(256) void attn_mfma(
    const u16* __restrict__ q_all, const u16* __restrict__ k_all,
    const u16* __restrict__ vt_all, const u16* __restrict__ bm_all,
    u16* __restrict__ ctx_all) {
  __shared__ u16 Ks[2][64 * 64];    // 8 KB x2
  __shared__ u16 Vs[2][64 * 64];    // 8 KB x2
  __shared__ u16 epi[4][32 * 72];   // per-wave epilogue transpose
  const int t = threadIdx.x, lane = t & 63, wave = t >> 6;
  const int l15 = lane & 15, quad = lane >> 4;

  // XCD clustering: 8 q-blocks of one (side,b,h) per XCD
  const int f = blockIdx.x;
  const int g = f & 7, r0 = f >> 3;
  const int combo = g * 8 + (r0 >> 3);  // 0..63
  const int x = r0 & 7;                 // q-block 0..7
  const int side = combo >> 5, b = (combo >> 3) & 3, h = combo & 7;

  const size_t HALF = 2097152;
  const u16* Q = q_all + side * HALF;
  const u16* K = k_all + (1 - side) * HALF;
  const u16* Vt = vt_all + (1 - side) * HALF;
  const u16* bm = bm_all + side * (size_t)4194304;
  u16* ctx = ctx_all + side * HALF;
  const int qbase = x * 128 + wave * 32;
  const int q16g = qbase >> 4;

  // Q B-frags: B[n=l15 -> q][k=quad*8+j -> d], 2 q-tiles x 2 d-halves
  short8 qb[2][2];
#pragma unroll
  for (int s = 0; s < 2; ++s) {
    const u16* qp = Q + (size_t)(b * 1024 + qbase + s * 16 + l15) * 512 + h * 64 + quad * 8;
    qb[s][0] = *(const short8*)qp;
    qb[s][1] = *(const short8*)(qp + 32);
  }

  short8 onesA;
#pragma unroll
  for (int j = 0; j < 8; ++j) onesA[j] = (short)0x3F80;

  floatx4 Oc[4][2];  // O^T tiles [d-tile][q-tile]
  floatx4 Dacc[2];
#pragma unroll
  for (int s = 0; s < 2; ++s) {
    Dacc[s] = (floatx4){0.f, 0.f, 0.f, 0.f};
#pragma unroll
    for (int nb = 0; nb < 4; ++nb) Oc[nb][s] = (floatx4){0.f, 0.f, 0.f, 0.f};
  }

#define STAGE(buf, k0)                                                             \
  {                                                                                \
    _Pragma("unroll") for (int i = 0; i < 2; ++i) {                                \
      int s = t + i * 256, row = s >> 3, pseg = s & 7, lseg = pseg ^ (row & 7);    \
      gload_lds16(K + (size_t)(b * 1024 + (k0) + row) * 512 + h * 64 + lseg * 8,   \
                  &Ks[buf][s * 8]);                                                \
      gload_lds16(Vt + ((size_t)(b * 8 + h) * 64 + row) * 1024 + (k0) + lseg * 8,  \
                  &Vs[buf][s * 8]);                                                \
    }                                                                              \
  }

  STAGE(0, 0)

  for (int it = 0; it < 16; ++it) {
    const int cur = it & 1;
    __syncthreads();
    if (it < 15) STAGE(cur ^ 1, it * 64 + 64)

    // bm fragments: lane=(q=l15,quad), i=kb*4+r -> k = it*64+kb*16+quad*4+r
    short8 bmv[2][2];
#pragma unroll
    for (int s = 0; s < 2; ++s) {
      const u16* bp = bm + ((((size_t)b * 64 + q16g + s) * 16 + it) * 64 + lane) * 16;
      bmv[s][0] = *(const short8*)bp;
      bmv[s][1] = *(const short8*)(bp + 8);
    }

    // ---- S^T = K.Q^T - 64 : tiles [key-tile kb][q-tile s] ----
    floatx4 St[2][4];
#pragma unroll
    for (int s = 0; s < 2; ++s)
#pragma unroll
      for (int kb = 0; kb < 4; ++kb) St[s][kb] = (floatx4){-64.f, -64.f, -64.f, -64.f};
#pragma unroll
    for (int kb = 0; kb < 4; ++kb) {
      int krow = kb * 16 + l15;
      short8 kf0 = *(const short8*)&Ks[cur][krow * 64 + ((quad ^ (krow & 7)) * 8)];
      short8 kf1 = *(const short8*)&Ks[cur][krow * 64 + (((4 + quad) ^ (krow & 7)) * 8)];
#pragma unroll
      for (int s = 0; s < 2; ++s) {
        St[s][kb] = MFMA16(kf0, qb[s][0], St[s][kb]);
        St[s][kb] = MFMA16(kf1, qb[s][1], St[s][kb]);
      }
    }

    // ---- p = exp2(S^T + bm); pack pairs (keys 4q+0,1 / 4q+2,3) ----
    unsigned pka[2][4], pkb[2][4];
#pragma unroll
    for (int s = 0; s < 2; ++s)
#pragma unroll
      for (int kb = 0; kb < 4; ++kb) {
        float pv[4];
#pragma unroll
        for (int r = 0; r < 4; ++r) {
          int i = kb * 4 + r;
          float bmf = bf2f((u16)((i < 8) ? bmv[s][0][i] : bmv[s][1][i - 8]));
          pv[r] = fast_exp2(St[s][kb][r] + bmf);
        }
        union { __hip_bfloat162 h; unsigned u; } c0, c1;
        c0.h = __float22bfloat162_rn(make_float2(pv[0], pv[1]));
        c1.h = __float22bfloat162_rn(make_float2(pv[2], pv[3]));
        pka[s][kb] = c0.u;
        pkb[s][kb] = c1.u;
      }

    // ---- P^T B-frags via permlane swaps; denom via ones MFMA ----
    short8 Pb[2][2];
#pragma unroll
    for (int s = 0; s < 2; ++s)
#pragma unroll
      for (int ks = 0; ks < 2; ++ks) {
        unsigned a0 = pka[s][2 * ks], a1 = pka[s][2 * ks + 1];
        unsigned b0 = pkb[s][2 * ks], b1 = pkb[s][2 * ks + 1];
        plswap32(a0, a1); plswap16(a0, a1);  // a0=keys(8Q+0,1), a1=keys(8Q+4,5)
        plswap32(b0, b1); plswap16(b0, b1);  // b0=keys(8Q+2,3), b1=keys(8Q+6,7)
        union { short8 s8; unsigned u[4]; } fb;
        fb.u[0] = a0; fb.u[1] = b0; fb.u[2] = a1; fb.u[3] = b1;
        Pb[s][ks] = fb.s8;
        Dacc[s] = MFMA16(onesA, fb.s8, Dacc[s]);
      }

    // ---- O^T += V^T.P^T ----
#pragma unroll
    for (int nb = 0; nb < 4; ++nb) {
      int vrow = nb * 16 + l15;
#pragma unroll
      for (int ks = 0; ks < 2; ++ks) {
        short8 vf = *(const short8*)&Vs[cur][vrow * 64 + ((((ks * 4 + quad)) ^ (vrow & 7)) * 8)];
        Oc[nb][0] = MFMA16(vf, Pb[0][ks], Oc[nb][0]);
        Oc[nb][1] = MFMA16(vf, Pb[1][ks], Oc[nb][1]);
      }
    }
  }

  // ---- epilogue: normalize (denom aligned at same lane), per-wave LDS transpose ----
  u16* eb = &epi[wave][0];  // [32][72]
#pragma unroll
  for (int s = 0; s < 2; ++s) {
    float dv = Dacc[s][0];
    float inv = dv > 0.f ? 1.f / dv : 0.f;
#pragma unroll
    for (int nb = 0; nb < 4; ++nb) {
      union { __hip_bfloat162 h; unsigned u; } w0, w1;
      w0.h = __float22bfloat162_rn(make_float2(Oc[nb][s][0] * inv, Oc[nb][s][1] * inv));
      w1.h = __float22bfloat162_rn(make_float2(Oc[nb][s][2] * inv, Oc[nb][s][3] * inv));
      union { unsigned u[2]; unsigned long long ull; } pk;
      pk.u[0] = w0.u; pk.u[1] = w1.u;
      *(unsigned long long*)&eb[(s * 16 + l15) * 72 + nb * 16 + quad * 4] = pk.ull;
    }
  }
  // same-wave DS ops are in-order: no barrier needed
#pragma unroll
  for (int p = 0; p < 4; ++p) {
    int row = p * 8 + (lane >> 3);
    int cs = (lane & 7) * 8;
    short8 v = *(const short8*)&eb[row * 72 + cs];
    *(short8*)(ctx + (size_t)(b * 1024 + qbase + row) * 512 + h * 64 + cs) = v;
  }
}

extern "C" void kernel_launch(void* const* d_in, const int* in_sizes, int n_in,
                              void* d_out, int out_size, void* d_ws, size_t ws_size,
                              hipStream_t stream) {
  const float* u_enc = (const float*)d_in[0];
  const float* e_enc = (const float*)d_in[1];
  const float* logit_bpp = (const float*)d_in[2];
  const int* ue_mask = (const int*)d_in[3];
  const int* eu_mask = (const int*)d_in[4];
  const float* wq_k = (const float*)d_in[5];
  const float* wq_b = (const float*)d_in[6];
  const float* wk_k = (const float*)d_in[7];
  const float* wk_b = (const float*)d_in[8];
  const float* wv_k = (const float*)d_in[9];
  const float* wv_b = (const float*)d_in[10];
  const float* wo_k = (const float*)d_in[11];
  const float* wo_b = (const float*)d_in[12];
  const float* bpp_w = (const float*)d_in[13];
  const float* bpp_b = (const float*)d_in[14];

  float* out = (float*)d_out;

  u16* ws16 = (u16*)d_ws;
  u16* ab    = ws16;                     // 4,194,304 u16
  u16* Wt    = ab + 4194304;             // 1,048,576
  u16* q_all = Wt + 1048576;             // 4,194,304
  u16* k_all = q_all + 4194304;          // 4,194,304
  u16* v_all = k_all + 4194304;          // 4,194,304
  u16* ctx   = v_all + 4194304;          // 4,194,304
  u16* bm    = ctx + 4194304;            // 8,388,608
  float* bias_all = (float*)(bm + 8388608);  // 2048 f32
  u16* vt = ab;                          // alias: ab dead after gemm<0>

  prep<<<9224, 256, 0, stream>>>(u_enc, e_enc, wq_k, wk_k, wv_k, wo_k,
                                 wq_b, wk_b, wv_b, wo_b, logit_bpp,
                                 ue_mask, eu_mask, bpp_w, bpp_b,
                                 ab, Wt, bias_all, bm);
  gemm_mfma<0><<<dim3(64, 12), 256, 0, stream>>>(ab, Wt, bias_all, nullptr,
                                                 q_all, k_all, v_all);
  vt_trans<<<dim3(16, 8, 8), 256, 0, stream>>>(v_all, vt);
  attn_mfma<<<512, 256, 0, stream>>>(q_all, k_all, vt, bm, ctx);
  gemm_mfma<1><<<dim3(64, 4), 256, 0, stream>>>(ctx, Wt + 786432, bias_all + 1536,
                                                out, nullptr, nullptr, nullptr);
}